// Round 16
// baseline (407.392 us; speedup 1.0000x reference)
//
#include <hip/hip_runtime.h>
#include <hip/hip_bf16.h>
#include <cstdint>

#define TB 256

typedef __attribute__((ext_vector_type(8))) short bf16x8;
typedef __attribute__((ext_vector_type(4))) float f32x4;
typedef __attribute__((ext_vector_type(2))) float f32x2;

__device__ __forceinline__ float lrelu_exp(float e){
  e = e > 0.0f ? e : 0.2f * e;
  return __expf(e);
}
__device__ __forceinline__ unsigned short f2bf(float f){
  unsigned u = __float_as_uint(f);
  u = (u + 0x7fffu + ((u >> 16) & 1u)) >> 16;   // RNE
  return (unsigned short)u;
}
__device__ __forceinline__ float lof(unsigned u){ return __uint_as_float(u << 16); }
__device__ __forceinline__ float hif(unsigned u){ return __uint_as_float(u & 0xffff0000u); }
__device__ __forceinline__ unsigned pack2(float a, float b){
  return (unsigned)f2bf(a) | ((unsigned)f2bf(b) << 16);
}

// ================= CSR build via 2-level bucket sort (LDS atomics only) =================
// buckets of 256 nodes (bin = dst >> 8); edge chunks of 8192.

// ---- kA: per-chunk coarse histogram -> counts[bin][block] ----
__global__ __launch_bounds__(256) void k_cnt(const int* __restrict__ ei, int E, int n,
                                             int* __restrict__ counts, int B, int NBK){
  __shared__ int h[512];
  int t = threadIdx.x;
  for (int i = t; i < NBK; i += 256) h[i] = 0;
  __syncthreads();
  int base = blockIdx.x * 8192;
  int end = base + 8192; if (end > E) end = E;
  for (int e = base + t; e < end; e += 256){
    int d = ei[E + e];
    if ((unsigned)d < (unsigned)n) atomicAdd(&h[d >> 8], 1);
  }
  __syncthreads();
  for (int i = t; i < NBK; i += 256) counts[i * B + blockIdx.x] = h[i];
}

// ---- kB: exclusive scan of counts (bin-major) + bucket starts ----
__global__ __launch_bounds__(256) void k_cscan(int* __restrict__ counts, int total,
                                               int* __restrict__ bstart, int B, int NBK){
  __shared__ int sums[256];
  int t = threadIdx.x;
  int CH = (total + 255) >> 8;
  int start = t * CH;
  int s = 0;
  for (int i = 0; i < CH; ++i){
    int idx = start + i;
    if (idx < total) s += counts[idx];
  }
  sums[t] = s;
  __syncthreads();
  for (int off = 1; off < 256; off <<= 1){
    int add = (t >= off) ? sums[t - off] : 0;
    __syncthreads();
    sums[t] += add;
    __syncthreads();
  }
  int run = sums[t] - s;                    // exclusive base for this chunk
  for (int i = 0; i < CH; ++i){
    int idx = start + i;
    if (idx < total){ int c = counts[idx]; counts[idx] = run; run += c; }
  }
  if (t == 255) bstart[NBK] = run;          // grand total (valid edges)
  __syncthreads();
  for (int b = t; b < NBK; b += 256) bstart[b] = counts[b * B];
}

// ---- kC: scatter (src,dst) pairs into bucket-contiguous order ----
__global__ __launch_bounds__(256) void k_bscat(const int* __restrict__ ei, int E, int n,
                                               const int* __restrict__ counts, int B,
                                               int2* __restrict__ pairs, int NBK){
  __shared__ int cur[512];
  int t = threadIdx.x;
  for (int i = t; i < NBK; i += 256) cur[i] = counts[i * B + blockIdx.x];
  __syncthreads();
  int base = blockIdx.x * 8192;
  int end = base + 8192; if (end > E) end = E;
  for (int e = base + t; e < end; e += 256){
    int s = ei[e], d = ei[E + e];
    if ((unsigned)d >= (unsigned)n || (unsigned)s >= (unsigned)n) continue;
    int r = atomicAdd(&cur[d >> 8], 1);
    pairs[r] = make_int2(s, d);
  }
}

// ---- kD: per-bucket fine histogram + scan -> deg/excl/col ----
__global__ __launch_bounds__(256) void k_bucket(const int2* __restrict__ pairs, const int* __restrict__ bstart,
                                                int n, int* __restrict__ deg, int* __restrict__ excl,
                                                int* __restrict__ col){
  __shared__ int hist[256];
  __shared__ int sums[256];
  int t = threadIdx.x;
  int b = blockIdx.x;
  int S = bstart[b], T = bstart[b + 1];
  int base = b << 8;
  hist[t] = 0;
  __syncthreads();
  for (int e = S + t; e < T; e += 256)
    atomicAdd(&hist[pairs[e].y - base], 1);
  __syncthreads();
  int v = hist[t];
  sums[t] = v;
  __syncthreads();
  for (int off = 1; off < 256; off <<= 1){
    int add = (t >= off) ? sums[t - off] : 0;
    __syncthreads();
    sums[t] += add;
    __syncthreads();
  }
  int loc = sums[t] - v;                   // local exclusive offset
  int node = base + t;
  if (node < n){ deg[node] = v; excl[node] = S + loc; }
  __syncthreads();
  hist[t] = loc;                           // reuse as cursor
  __syncthreads();
  for (int e = S + t; e < T; e += 256){
    int2 pr = pairs[e];
    int r = atomicAdd(&hist[pr.y - base], 1);
    col[S + r] = pr.x;
  }
}

// ---------------- GEMM1 (MFMA bf16 -> fp8 rows + fused att1) ----------------
__global__ __launch_bounds__(256) void k_gemm1(const float* __restrict__ x, const float* __restrict__ W1,
                                               const float* __restrict__ asw, const float* __restrict__ adw,
                                               unsigned char* __restrict__ hq,
                                               float* __restrict__ a_s1, float* __restrict__ a_d1, int n){
  __shared__ __align__(16) char smem[45056];
  unsigned short (*As)[40]  = (unsigned short(*)[40])smem;            // 10240 B
  unsigned short (*Bs)[136] = (unsigned short(*)[136])(smem + 10240); // 34816 B
  unsigned short (*T)[136]  = (unsigned short(*)[136])smem;           // epilogue alias
  int t = threadIdx.x;
  int l = t & 63, wid = t >> 6;
  int wm = wid >> 1, wn = wid & 1;
  int node0 = (int)blockIdx.x * 128;
  {
    int k = t >> 1;
    int ch = (t & 1) * 64;
    const float4* wr = (const float4*)(W1 + (size_t)k * 128 + ch);
    #pragma unroll
    for (int u = 0; u < 16; ++u){
      float4 f = wr[u];
      int c = ch + u * 4;
      Bs[c + 0][k] = f2bf(f.x);
      Bs[c + 1][k] = f2bf(f.y);
      Bs[c + 2][k] = f2bf(f.z);
      Bs[c + 3][k] = f2bf(f.w);
    }
  }
  f32x4 acc[4][4];
  #pragma unroll
  for (int i = 0; i < 4; ++i)
    #pragma unroll
    for (int j = 0; j < 4; ++j) acc[i][j] = (f32x4){0.f, 0.f, 0.f, 0.f};

  int lrow = l & 15, lk8 = (l >> 4) * 8;
  for (int kc = 0; kc < 4; ++kc){
    __syncthreads();
    {
      int row = t >> 1, kh = t & 1;
      int gn = node0 + row;
      const float4* src = (const float4*)(x + (size_t)gn * 128 + kc * 32 + kh * 16);
      float4 z = make_float4(0.f, 0.f, 0.f, 0.f);
      float4 f0 = (gn < n) ? src[0] : z;
      float4 f1 = (gn < n) ? src[1] : z;
      float4 f2 = (gn < n) ? src[2] : z;
      float4 f3 = (gn < n) ? src[3] : z;
      uint4 p0, p1;
      p0.x = pack2(f0.x, f0.y); p0.y = pack2(f0.z, f0.w);
      p0.z = pack2(f1.x, f1.y); p0.w = pack2(f1.z, f1.w);
      p1.x = pack2(f2.x, f2.y); p1.y = pack2(f2.z, f2.w);
      p1.z = pack2(f3.x, f3.y); p1.w = pack2(f3.z, f3.w);
      *(uint4*)&As[row][kh * 16]     = p0;
      *(uint4*)&As[row][kh * 16 + 8] = p1;
    }
    __syncthreads();
    bf16x8 a[4], b[4];
    #pragma unroll
    for (int mi = 0; mi < 4; ++mi)
      a[mi] = *(const bf16x8*)&As[wm * 64 + mi * 16 + lrow][lk8];
    #pragma unroll
    for (int ni = 0; ni < 4; ++ni)
      b[ni] = *(const bf16x8*)&Bs[wn * 64 + ni * 16 + lrow][kc * 32 + lk8];
    #pragma unroll
    for (int mi = 0; mi < 4; ++mi)
      #pragma unroll
      for (int ni = 0; ni < 4; ++ni)
        acc[mi][ni] = __builtin_amdgcn_mfma_f32_16x16x32_bf16(a[mi], b[ni], acc[mi][ni], 0, 0, 0);
  }
  __syncthreads();                      // As/Bs dead; T takes over
  int rg = (l >> 4) * 4;
  #pragma unroll
  for (int mi = 0; mi < 4; ++mi)
    #pragma unroll
    for (int j = 0; j < 4; ++j){
      int nl = wm * 64 + mi * 16 + rg + j;
      #pragma unroll
      for (int ni = 0; ni < 4; ++ni)
        T[nl][wn * 64 + ni * 16 + lrow] = f2bf(acc[mi][ni][j]);
    }
  __syncthreads();
  // fused att1 + fp8 row emit: 2 threads/row, 64 ch each (4 heads)
  {
    int r = t >> 1, half = t & 1;
    int gn = node0 + r;
    float ssv[4], ddv[4];
    #pragma unroll
    for (int c = 0; c < 4; ++c){
      int h = half * 4 + c;
      uint4 q0 = *(const uint4*)&T[r][half * 64 + c * 16];
      uint4 q1 = *(const uint4*)&T[r][half * 64 + c * 16 + 8];
      unsigned wv[8] = {q0.x, q0.y, q0.z, q0.w, q1.x, q1.y, q1.z, q1.w};
      float f[16];
      #pragma unroll
      for (int u = 0; u < 8; ++u){ f[2 * u] = lof(wv[u]); f[2 * u + 1] = hif(wv[u]); }
      float ss = 0.f, dd = 0.f;
      #pragma unroll
      for (int u = 0; u < 16; ++u){
        ss = fmaf(f[u], asw[h * 16 + u], ss);
        dd = fmaf(f[u], adw[h * 16 + u], dd);
      }
      ssv[c] = ss; ddv[c] = dd;
      uint4 pk;
      pk.x = (unsigned)__builtin_amdgcn_cvt_pk_fp8_f32(f[0],  f[1],  0, 0);
      pk.x = (unsigned)__builtin_amdgcn_cvt_pk_fp8_f32(f[2],  f[3],  (int)pk.x, 1);
      pk.y = (unsigned)__builtin_amdgcn_cvt_pk_fp8_f32(f[4],  f[5],  0, 0);
      pk.y = (unsigned)__builtin_amdgcn_cvt_pk_fp8_f32(f[6],  f[7],  (int)pk.y, 1);
      pk.z = (unsigned)__builtin_amdgcn_cvt_pk_fp8_f32(f[8],  f[9],  0, 0);
      pk.z = (unsigned)__builtin_amdgcn_cvt_pk_fp8_f32(f[10], f[11], (int)pk.z, 1);
      pk.w = (unsigned)__builtin_amdgcn_cvt_pk_fp8_f32(f[12], f[13], 0, 0);
      pk.w = (unsigned)__builtin_amdgcn_cvt_pk_fp8_f32(f[14], f[15], (int)pk.w, 1);
      if (gn < n) *(uint4*)(hq + (size_t)gn * 128 + half * 64 + c * 16) = pk;
    }
    if (gn < n){
      *(float4*)(a_s1 + (size_t)gn * 8 + half * 4) = make_float4(ssv[0], ssv[1], ssv[2], ssv[3]);
      *(float4*)(a_d1 + (size_t)gn * 8 + half * 4) = make_float4(ddv[0], ddv[1], ddv[2], ddv[3]);
    }
  }
}

// ---------------- agg1: fp8 rows, 4 edge-groups of 16 lanes (uint2 = 8 ch/lane) ----------------
__global__ __launch_bounds__(256) void k_agg1(const unsigned char* __restrict__ hq, const float* __restrict__ a_s,
    const float* __restrict__ a_d, const int* __restrict__ col,
    const int* __restrict__ excl, const int* __restrict__ deg,
    const float* __restrict__ b1, unsigned short* __restrict__ out1b, int n){
  int tl = threadIdx.x & 63;
  int node = blockIdx.x * 4 + (threadIdx.x >> 6);
  if (node >= n) return;
  int g  = tl >> 4;          // edge group 0..3
  int il = tl & 15;          // channels [8il, 8il+8)
  int h  = il >> 1;
  float adn = a_d[(size_t)node * 8 + h];
  float a0 = 0.f, a1 = 0.f, a2 = 0.f, a3 = 0.f, a4 = 0.f, a5 = 0.f, a6 = 0.f, a7 = 0.f;
  float denom = 0.f;
  if (g == 0){
    float wSelf = lrelu_exp(a_s[(size_t)node * 8 + h] + adn);
    uint2 hv = *(const uint2*)(hq + (size_t)node * 128 + il * 8);
    f32x2 l0 = __builtin_amdgcn_cvt_pk_f32_fp8((int)hv.x, false);
    f32x2 h0 = __builtin_amdgcn_cvt_pk_f32_fp8((int)hv.x, true);
    f32x2 l1 = __builtin_amdgcn_cvt_pk_f32_fp8((int)hv.y, false);
    f32x2 h1 = __builtin_amdgcn_cvt_pk_f32_fp8((int)hv.y, true);
    a0 = wSelf * l0[0]; a1 = wSelf * l0[1]; a2 = wSelf * h0[0]; a3 = wSelf * h0[1];
    a4 = wSelf * l1[0]; a5 = wSelf * l1[1]; a6 = wSelf * h1[0]; a7 = wSelf * h1[1];
    denom = wSelf;
  }
  int pp = excl[node];
  int end = pp + deg[node];
  for (; pp + 16 <= end; pp += 16){
    int s[4]; float as[4]; uint2 v[4];
    #pragma unroll
    for (int u = 0; u < 4; ++u) s[u] = col[pp + 4 * u + g];
    #pragma unroll
    for (int u = 0; u < 4; ++u) as[u] = a_s[(size_t)s[u] * 8 + h];
    #pragma unroll
    for (int u = 0; u < 4; ++u) v[u] = *(const uint2*)(hq + (size_t)s[u] * 128 + il * 8);
    #pragma unroll
    for (int u = 0; u < 4; ++u){
      float w = lrelu_exp(as[u] + adn);
      f32x2 l0 = __builtin_amdgcn_cvt_pk_f32_fp8((int)v[u].x, false);
      f32x2 h0 = __builtin_amdgcn_cvt_pk_f32_fp8((int)v[u].x, true);
      f32x2 l1 = __builtin_amdgcn_cvt_pk_f32_fp8((int)v[u].y, false);
      f32x2 h1 = __builtin_amdgcn_cvt_pk_f32_fp8((int)v[u].y, true);
      a0 = fmaf(w, l0[0], a0); a1 = fmaf(w, l0[1], a1);
      a2 = fmaf(w, h0[0], a2); a3 = fmaf(w, h0[1], a3);
      a4 = fmaf(w, l1[0], a4); a5 = fmaf(w, l1[1], a5);
      a6 = fmaf(w, h1[0], a6); a7 = fmaf(w, h1[1], a7);
      denom += w;
    }
  }
  for (; pp + 4 <= end; pp += 4){
    int s0 = col[pp + g];
    float w = lrelu_exp(a_s[(size_t)s0 * 8 + h] + adn);
    uint2 v0 = *(const uint2*)(hq + (size_t)s0 * 128 + il * 8);
    f32x2 l0 = __builtin_amdgcn_cvt_pk_f32_fp8((int)v0.x, false);
    f32x2 h0 = __builtin_amdgcn_cvt_pk_f32_fp8((int)v0.x, true);
    f32x2 l1 = __builtin_amdgcn_cvt_pk_f32_fp8((int)v0.y, false);
    f32x2 h1 = __builtin_amdgcn_cvt_pk_f32_fp8((int)v0.y, true);
    a0 = fmaf(w, l0[0], a0); a1 = fmaf(w, l0[1], a1);
    a2 = fmaf(w, h0[0], a2); a3 = fmaf(w, h0[1], a3);
    a4 = fmaf(w, l1[0], a4); a5 = fmaf(w, l1[1], a5);
    a6 = fmaf(w, h1[0], a6); a7 = fmaf(w, h1[1], a7);
    denom += w;
  }
  if (pp + g < end){
    int s0 = col[pp + g];
    float w = lrelu_exp(a_s[(size_t)s0 * 8 + h] + adn);
    uint2 v0 = *(const uint2*)(hq + (size_t)s0 * 128 + il * 8);
    f32x2 l0 = __builtin_amdgcn_cvt_pk_f32_fp8((int)v0.x, false);
    f32x2 h0 = __builtin_amdgcn_cvt_pk_f32_fp8((int)v0.x, true);
    f32x2 l1 = __builtin_amdgcn_cvt_pk_f32_fp8((int)v0.y, false);
    f32x2 h1 = __builtin_amdgcn_cvt_pk_f32_fp8((int)v0.y, true);
    a0 = fmaf(w, l0[0], a0); a1 = fmaf(w, l0[1], a1);
    a2 = fmaf(w, h0[0], a2); a3 = fmaf(w, h0[1], a3);
    a4 = fmaf(w, l1[0], a4); a5 = fmaf(w, l1[1], a5);
    a6 = fmaf(w, h1[0], a6); a7 = fmaf(w, h1[1], a7);
    denom += w;
  }
  #pragma unroll
  for (int off = 16; off <= 32; off <<= 1){
    a0 += __shfl_xor(a0, off); a1 += __shfl_xor(a1, off);
    a2 += __shfl_xor(a2, off); a3 += __shfl_xor(a3, off);
    a4 += __shfl_xor(a4, off); a5 += __shfl_xor(a5, off);
    a6 += __shfl_xor(a6, off); a7 += __shfl_xor(a7, off);
    denom += __shfl_xor(denom, off);
  }
  float inv = 1.0f / denom;
  float4 bb0 = *(const float4*)(b1 + il * 8);
  float4 bb1 = *(const float4*)(b1 + il * 8 + 4);
  float o0 = fmaf(a0, inv, bb0.x); o0 = o0 > 0.f ? o0 : 0.f;
  float o1 = fmaf(a1, inv, bb0.y); o1 = o1 > 0.f ? o1 : 0.f;
  float o2 = fmaf(a2, inv, bb0.z); o2 = o2 > 0.f ? o2 : 0.f;
  float o3 = fmaf(a3, inv, bb0.w); o3 = o3 > 0.f ? o3 : 0.f;
  float o4 = fmaf(a4, inv, bb1.x); o4 = o4 > 0.f ? o4 : 0.f;
  float o5 = fmaf(a5, inv, bb1.y); o5 = o5 > 0.f ? o5 : 0.f;
  float o6 = fmaf(a6, inv, bb1.z); o6 = o6 > 0.f ? o6 : 0.f;
  float o7 = fmaf(a7, inv, bb1.w); o7 = o7 > 0.f ? o7 : 0.f;
  if (g == 0){
    uint4 o;
    o.x = pack2(o0, o1); o.y = pack2(o2, o3);
    o.z = pack2(o4, o5); o.w = pack2(o6, o7);
    *(uint4*)(out1b + (size_t)node * 128 + il * 8) = o;
  }
}

// ---------------- gemm2 + fused att2 -> fp8 rows [N][64B] with a_s embedded at byte 40 ----------------
__global__ __launch_bounds__(256) void k_gemm2a(const unsigned short* __restrict__ ab, const float* __restrict__ W2,
                                                const float* __restrict__ asw2, const float* __restrict__ adw2,
                                                unsigned char* __restrict__ h2q,
                                                float* __restrict__ a_d, int n){
  __shared__ unsigned short xs[32][256];   // 16 KB (bf16); epilogue alias: RB[256][64] bytes
  __shared__ float ws[128][40];            // 20 KB
  __shared__ float ssb[256], ddb[256];     // 2 KB
  int t = threadIdx.x;
  for (int i = t; i < 128 * 40; i += 256) (&ws[0][0])[i] = W2[i];
  ssb[t] = 0.f; ddb[t] = 0.f;
  int ng = t & 63, cg = t >> 6;
  int node0 = blockIdx.x * 256;
  float acc[4][10];
  #pragma unroll
  for (int i = 0; i < 4; ++i)
    #pragma unroll
    for (int j = 0; j < 10; ++j) acc[i][j] = 0.0f;

  for (int kc = 0; kc < 4; ++kc){
    int k0 = kc * 32;
    __syncthreads();
    {
      int gn = node0 + t;
      uint4 q0, q1, r0, r1;
      uint4 z = make_uint4(0, 0, 0, 0);
      if (gn < n){
        const uint4* src = (const uint4*)(ab + (size_t)gn * 128 + k0);
        q0 = src[0]; q1 = src[1]; r0 = src[2]; r1 = src[3];
      } else { q0 = z; q1 = z; r0 = z; r1 = z; }
      unsigned w16[8] = {q0.x, q0.y, q0.z, q0.w, q1.x, q1.y, q1.z, q1.w};
      #pragma unroll
      for (int j = 0; j < 8; ++j){
        xs[j * 2][t]     = (unsigned short)(w16[j] & 0xffffu);
        xs[j * 2 + 1][t] = (unsigned short)(w16[j] >> 16);
      }
      unsigned w16b[8] = {r0.x, r0.y, r0.z, r0.w, r1.x, r1.y, r1.z, r1.w};
      #pragma unroll
      for (int j = 0; j < 8; ++j){
        xs[16 + j * 2][t]     = (unsigned short)(w16b[j] & 0xffffu);
        xs[16 + j * 2 + 1][t] = (unsigned short)(w16b[j] >> 16);
      }
    }
    __syncthreads();
    #pragma unroll 4
    for (int k = 0; k < 32; ++k){
      float xv[4];
      #pragma unroll
      for (int i = 0; i < 4; ++i) xv[i] = __uint_as_float(((unsigned)xs[k][ng + 64 * i]) << 16);
      float wv[10];
      #pragma unroll
      for (int j = 0; j < 10; ++j) wv[j] = ws[k0 + k][cg * 10 + j];
      #pragma unroll
      for (int i = 0; i < 4; ++i)
        #pragma unroll
        for (int j = 0; j < 10; ++j) acc[i][j] = fmaf(xv[i], wv[j], acc[i][j]);
    }
  }
  // fused att2 partial dots
  float asl[10], adl[10];
  #pragma unroll
  for (int j = 0; j < 10; ++j){ asl[j] = asw2[cg * 10 + j]; adl[j] = adw2[cg * 10 + j]; }
  #pragma unroll
  for (int i = 0; i < 4; ++i){
    float ssi = 0.f, ddi = 0.f;
    #pragma unroll
    for (int j = 0; j < 10; ++j){
      ssi = fmaf(acc[i][j], asl[j], ssi);
      ddi = fmaf(acc[i][j], adl[j], ddi);
    }
    atomicAdd(&ssb[ng + 64 * i], ssi);
    atomicAdd(&ddb[ng + 64 * i], ddi);
  }
  __syncthreads();                         // xs dead, ssb/ddb final
  unsigned char* RB = (unsigned char*)xs;  // 256 rows x 64 B
  #pragma unroll
  for (int i = 0; i < 4; ++i){
    int row = ng + 64 * i;
    unsigned char* dst = &RB[row * 64 + cg * 10];
    #pragma unroll
    for (int j = 0; j < 10; j += 2){
      int p2 = __builtin_amdgcn_cvt_pk_fp8_f32(acc[i][j], acc[i][j + 1], 0, 0);
      dst[j]     = (unsigned char)(p2 & 0xff);
      dst[j + 1] = (unsigned char)((p2 >> 8) & 0xff);
    }
  }
  *(float*)&RB[t * 64 + 40] = ssb[t];      // embed a_s at byte 40
  __syncthreads();
  {
    int gn = node0 + t;
    if (gn < n){
      a_d[gn] = ddb[t];
      uint4* drow = (uint4*)(h2q + (size_t)gn * 64);
      const uint4* srow = (const uint4*)&RB[t * 64];
      drow[0] = srow[0]; drow[1] = srow[1]; drow[2] = srow[2]; drow[3] = srow[3];
    }
  }
}

// ---------------- agg2 + log_softmax: 64B fp8 rows, 4 edge-groups of 16 lanes ----------------
__global__ __launch_bounds__(256) void k_agg2(const unsigned char* __restrict__ h2q,
    const float* __restrict__ a_d, const int* __restrict__ col,
    const int* __restrict__ excl, const int* __restrict__ deg,
    const float* __restrict__ b2, float* __restrict__ out, int n){
  int tl = threadIdx.x & 63;
  int node = blockIdx.x * 4 + (threadIdx.x >> 6);
  if (node >= n) return;
  int g = tl >> 4, il = tl & 15;
  bool ld  = il < 11;
  bool act = il < 10;                      // channels 4il..4il+3 (< 40)
  float adn = a_d[node];
  float a0 = 0.f, a1 = 0.f, a2 = 0.f, a3 = 0.f, denom = 0.f;
  if (g == 0){
    const unsigned* sr = (const unsigned*)(h2q + (size_t)node * 64);
    unsigned hv = ld ? sr[il] : 0u;
    float asf = __uint_as_float(__shfl(hv, 10));
    float wSelf = lrelu_exp(asf + adn);
    f32x2 lo = __builtin_amdgcn_cvt_pk_f32_fp8((int)hv, false);
    f32x2 hi = __builtin_amdgcn_cvt_pk_f32_fp8((int)hv, true);
    a0 = wSelf * lo[0]; a1 = wSelf * lo[1];
    a2 = wSelf * hi[0]; a3 = wSelf * hi[1];
    denom = wSelf;
  }
  int pp = excl[node];
  int end = pp + deg[node];
  for (; pp + 16 <= end; pp += 16){
    int s[4]; unsigned v[4];
    #pragma unroll
    for (int u = 0; u < 4; ++u) s[u] = col[pp + 4 * u + g];
    #pragma unroll
    for (int u = 0; u < 4; ++u) v[u] = ld ? *(const unsigned*)(h2q + (size_t)s[u] * 64 + il * 4) : 0u;
    #pragma unroll
    for (int u = 0; u < 4; ++u){
      float asf = __uint_as_float(__shfl(v[u], (g << 4) + 10));
      float w = lrelu_exp(asf + adn);
      f32x2 lo = __builtin_amdgcn_cvt_pk_f32_fp8((int)v[u], false);
      f32x2 hi = __builtin_amdgcn_cvt_pk_f32_fp8((int)v[u], true);
      a0 = fmaf(w, lo[0], a0); a1 = fmaf(w, lo[1], a1);
      a2 = fmaf(w, hi[0], a2); a3 = fmaf(w, hi[1], a3);
      denom += w;
    }
  }
  for (; pp + 4 <= end; pp += 4){
    int s0 = col[pp + g];
    unsigned v0 = ld ? *(const unsigned*)(h2q + (size_t)s0 * 64 + il * 4) : 0u;
    float asf = __uint_as_float(__shfl(v0, (g << 4) + 10));
    float w = lrelu_exp(asf + adn);
    f32x2 lo = __builtin_amdgcn_cvt_pk_f32_fp8((int)v0, false);
    f32x2 hi = __builtin_amdgcn_cvt_pk_f32_fp8((int)v0, true);
    a0 = fmaf(w, lo[0], a0); a1 = fmaf(w, lo[1], a1);
    a2 = fmaf(w, hi[0], a2); a3 = fmaf(w, hi[1], a3);
    denom += w;
  }
  if (pp + g < end){
    int s0 = col[pp + g];
    unsigned v0 = ld ? *(const unsigned*)(h2q + (size_t)s0 * 64 + il * 4) : 0u;
    float asf = __uint_as_float(__shfl(v0, (g << 4) + 10));
    float w = lrelu_exp(asf + adn);
    f32x2 lo = __builtin_amdgcn_cvt_pk_f32_fp8((int)v0, false);
    f32x2 hi = __builtin_amdgcn_cvt_pk_f32_fp8((int)v0, true);
    a0 = fmaf(w, lo[0], a0); a1 = fmaf(w, lo[1], a1);
    a2 = fmaf(w, hi[0], a2); a3 = fmaf(w, hi[1], a3);
    denom += w;
  }
  #pragma unroll
  for (int off = 16; off <= 32; off <<= 1){
    a0 += __shfl_xor(a0, off); a1 += __shfl_xor(a1, off);
    a2 += __shfl_xor(a2, off); a3 += __shfl_xor(a3, off);
    denom += __shfl_xor(denom, off);
  }
  float inv = 1.0f / denom;
  float4 bb = act ? *(const float4*)(b2 + il * 4) : make_float4(0.f, 0.f, 0.f, 0.f);
  float v0 = act ? fmaf(a0, inv, bb.x) : -1e30f;
  float v1 = act ? fmaf(a1, inv, bb.y) : -1e30f;
  float v2 = act ? fmaf(a2, inv, bb.z) : -1e30f;
  float v3 = act ? fmaf(a3, inv, bb.w) : -1e30f;
  float m = fmaxf(fmaxf(v0, v1), fmaxf(v2, v3));
  #pragma unroll
  for (int off = 8; off >= 1; off >>= 1) m = fmaxf(m, __shfl_xor(m, off));
  float S = act ? (__expf(v0 - m) + __expf(v1 - m) + __expf(v2 - m) + __expf(v3 - m)) : 0.f;
  #pragma unroll
  for (int off = 8; off >= 1; off >>= 1) S += __shfl_xor(S, off);
  float ls = __logf(S);
  if (act && g == 0){
    *(float4*)(out + (size_t)node * 40 + il * 4) =
      make_float4(v0 - m - ls, v1 - m - ls, v2 - m - ls, v3 - m - ls);
  }
}

extern "C" void kernel_launch(void* const* d_in, const int* in_sizes, int n_in,
                              void* d_out, int out_size, void* d_ws, size_t ws_size,
                              hipStream_t stream){
  const float* x    = (const float*)d_in[0];
  const int*   ei   = (const int*)d_in[1];          // int32 (jax x64 disabled)
  const float* W1   = (const float*)d_in[2];
  const float* as1w = (const float*)d_in[3];
  const float* ad1w = (const float*)d_in[4];
  const float* b1   = (const float*)d_in[5];
  const float* W2   = (const float*)d_in[6];
  const float* as2w = (const float*)d_in[7];
  const float* ad2w = (const float*)d_in[8];
  const float* b2   = (const float*)d_in[9];
  float* out = (float*)d_out;
  const int N = in_sizes[0] / 128;
  const int E = in_sizes[1] / 2;

  const int NBK = (N + 255) / 256;        // node buckets of 256
  const int B   = (E + 8191) / 8192;      // edge chunks of 8192

  char* p = (char*)d_ws;
  auto alloc = [&](size_t bytes) -> void* {
    void* r = (void*)p;
    p += (bytes + 511) & ~(size_t)511;
    return r;
  };
  int*            deg      = (int*)           alloc((size_t)N * 4);
  int*            excl     = (int*)           alloc((size_t)N * 4);
  int*            counts   = (int*)           alloc((size_t)NBK * B * 4);
  int*            bstart   = (int*)           alloc((size_t)(NBK + 1) * 4);
  int2*           pairs    = (int2*)          alloc((size_t)E * 8);
  int*            col      = (int*)           alloc((size_t)E * 4);
  float*          a_s1     = (float*)         alloc((size_t)N * 8 * 4);
  float*          a_d1     = (float*)         alloc((size_t)N * 8 * 4);
  unsigned short* out1b    = (unsigned short*)alloc((size_t)N * 128 * 2);
  unsigned char*  h1q      = (unsigned char*) alloc((size_t)N * 128);
  // layer-2 temporaries overlay h1q (dead after agg1): h2q = N*64 bytes
  unsigned char*  h2q  = h1q;
  float*          a_d2 = (float*)(h1q + (size_t)N * 64 + 256);

  int nG1 = (N + 127) / 128;

  k_gemm1 <<<nG1, 256, 0, stream>>>(x, W1, as1w, ad1w, h1q, a_s1, a_d1, N);
  k_cnt   <<<B, 256, 0, stream>>>(ei, E, N, counts, B, NBK);
  k_cscan <<<1, 256, 0, stream>>>(counts, NBK * B, bstart, B, NBK);
  k_bscat <<<B, 256, 0, stream>>>(ei, E, N, counts, B, pairs, NBK);
  k_bucket<<<NBK, 256, 0, stream>>>(pairs, bstart, N, deg, excl, col);
  k_agg1  <<<(N + 3) / 4, 256, 0, stream>>>(h1q, a_s1, a_d1, col, excl, deg, b1, out1b, N);
  k_gemm2a<<<(N + 255) / 256, 256, 0, stream>>>(out1b, W2, as2w, ad2w, h2q, a_d2, N);
  k_agg2  <<<(N + 3) / 4, 256, 0, stream>>>(h2q, a_d2, col, excl, deg, b2, out, N);
}

// Round 17
// 259.240 us; speedup vs baseline: 1.5715x; 1.5715x over previous
//
#include <hip/hip_runtime.h>
#include <hip/hip_bf16.h>
#include <cstdint>

#define TB 256

typedef __attribute__((ext_vector_type(8))) short bf16x8;
typedef __attribute__((ext_vector_type(4))) float f32x4;
typedef __attribute__((ext_vector_type(2))) float f32x2;

__device__ __forceinline__ float lrelu_exp(float e){
  e = e > 0.0f ? e : 0.2f * e;
  return __expf(e);
}
__device__ __forceinline__ unsigned short f2bf(float f){
  unsigned u = __float_as_uint(f);
  u = (u + 0x7fffu + ((u >> 16) & 1u)) >> 16;   // RNE
  return (unsigned short)u;
}
__device__ __forceinline__ float lof(unsigned u){ return __uint_as_float(u << 16); }
__device__ __forceinline__ float hif(unsigned u){ return __uint_as_float(u & 0xffff0000u); }
__device__ __forceinline__ unsigned pack2(float a, float b){
  return (unsigned)f2bf(a) | ((unsigned)f2bf(b) << 16);
}

// ================= CSR build via 2-level bucket sort (LDS atomics only) =================
// buckets of 256 nodes (bin = dst >> 8); edge chunks of 8192.

// ---- kA: per-chunk coarse histogram -> counts[bin][block] ----
__global__ __launch_bounds__(256) void k_cnt(const int* __restrict__ ei, int E, int n,
                                             int* __restrict__ counts, int B, int NBK){
  __shared__ int h[512];
  int t = threadIdx.x;
  for (int i = t; i < NBK; i += 256) h[i] = 0;
  __syncthreads();
  int base = blockIdx.x * 8192;
  int end = base + 8192; if (end > E) end = E;
  for (int e = base + t; e < end; e += 256){
    int d = ei[E + e];
    if ((unsigned)d < (unsigned)n) atomicAdd(&h[d >> 8], 1);
  }
  __syncthreads();
  for (int i = t; i < NBK; i += 256) counts[i * B + blockIdx.x] = h[i];
}

// ---- kB1: multi-block scan of counts, 2048/block ----
__global__ __launch_bounds__(256) void k_s1(int* __restrict__ counts, int total, int* __restrict__ partials){
  __shared__ int sums[256];
  int t = threadIdx.x;
  int base = blockIdx.x * 2048 + t * 8;
  int v[8]; int s = 0;
  #pragma unroll
  for (int i = 0; i < 8; ++i){ int idx = base + i; v[i] = (idx < total) ? counts[idx] : 0; s += v[i]; }
  sums[t] = s;
  __syncthreads();
  for (int off = 1; off < 256; off <<= 1){
    int add = (t >= off) ? sums[t - off] : 0;
    __syncthreads();
    sums[t] += add;
    __syncthreads();
  }
  int run = sums[t] - s;
  if (t == 255) partials[blockIdx.x] = sums[t];
  #pragma unroll
  for (int i = 0; i < 8; ++i){ int idx = base + i; if (idx < total) counts[idx] = run; run += v[i]; }
}

// ---- kB2: single-wave scan of partials; writes grand total to bstart[NBK] ----
__global__ void k_s2(int* __restrict__ partials, int nb, int* __restrict__ bstart, int NBK){
  int lane = threadIdx.x;
  int orig = (lane < nb) ? partials[lane] : 0;
  int v = orig;
  for (int off = 1; off < 64; off <<= 1){
    int u = __shfl_up(v, off);
    if (lane >= off) v += u;
  }
  if (lane < nb) partials[lane] = v - orig;
  if (lane == nb - 1) bstart[NBK] = v;     // inclusive total = all valid edges
}

// ---- kB3: add partials + extract bucket starts ----
__global__ __launch_bounds__(256) void k_s3(int* __restrict__ counts, int total,
                                            const int* __restrict__ partials, int B,
                                            int* __restrict__ bstart){
  int i = blockIdx.x * 256 + threadIdx.x;
  if (i >= total) return;
  int v = counts[i] + partials[i / 2048];
  counts[i] = v;
  if (i % B == 0) bstart[i / B] = v;
}

// ---- kC: scatter (src,dst) pairs into bucket-contiguous order ----
__global__ __launch_bounds__(256) void k_bscat(const int* __restrict__ ei, int E, int n,
                                               const int* __restrict__ counts, int B,
                                               int2* __restrict__ pairs, int NBK){
  __shared__ int cur[512];
  int t = threadIdx.x;
  for (int i = t; i < NBK; i += 256) cur[i] = counts[i * B + blockIdx.x];
  __syncthreads();
  int base = blockIdx.x * 8192;
  int end = base + 8192; if (end > E) end = E;
  for (int e = base + t; e < end; e += 256){
    int s = ei[e], d = ei[E + e];
    if ((unsigned)d >= (unsigned)n || (unsigned)s >= (unsigned)n) continue;
    int r = atomicAdd(&cur[d >> 8], 1);
    pairs[r] = make_int2(s, d);
  }
}

// ---- kD: per-bucket fine histogram + scan -> deg/excl/col ----
__global__ __launch_bounds__(256) void k_bucket(const int2* __restrict__ pairs, const int* __restrict__ bstart,
                                                int n, int* __restrict__ deg, int* __restrict__ excl,
                                                int* __restrict__ col){
  __shared__ int hist[256];
  __shared__ int sums[256];
  int t = threadIdx.x;
  int b = blockIdx.x;
  int S = bstart[b], T = bstart[b + 1];
  int base = b << 8;
  hist[t] = 0;
  __syncthreads();
  for (int e = S + t; e < T; e += 256)
    atomicAdd(&hist[pairs[e].y - base], 1);
  __syncthreads();
  int v = hist[t];
  sums[t] = v;
  __syncthreads();
  for (int off = 1; off < 256; off <<= 1){
    int add = (t >= off) ? sums[t - off] : 0;
    __syncthreads();
    sums[t] += add;
    __syncthreads();
  }
  int loc = sums[t] - v;                   // local exclusive offset
  int node = base + t;
  if (node < n){ deg[node] = v; excl[node] = S + loc; }
  __syncthreads();
  hist[t] = loc;                           // reuse as cursor
  __syncthreads();
  for (int e = S + t; e < T; e += 256){
    int2 pr = pairs[e];
    int r = atomicAdd(&hist[pr.y - base], 1);
    col[S + r] = pr.x;
  }
}

// ---------------- GEMM1 (MFMA bf16 -> fp8 rows + fused att1) ----------------
__global__ __launch_bounds__(256) void k_gemm1(const float* __restrict__ x, const float* __restrict__ W1,
                                               const float* __restrict__ asw, const float* __restrict__ adw,
                                               unsigned char* __restrict__ hq,
                                               float* __restrict__ a_s1, float* __restrict__ a_d1, int n){
  __shared__ __align__(16) char smem[45056];
  unsigned short (*As)[40]  = (unsigned short(*)[40])smem;            // 10240 B
  unsigned short (*Bs)[136] = (unsigned short(*)[136])(smem + 10240); // 34816 B
  unsigned short (*T)[136]  = (unsigned short(*)[136])smem;           // epilogue alias
  int t = threadIdx.x;
  int l = t & 63, wid = t >> 6;
  int wm = wid >> 1, wn = wid & 1;
  int node0 = (int)blockIdx.x * 128;
  {
    int k = t >> 1;
    int ch = (t & 1) * 64;
    const float4* wr = (const float4*)(W1 + (size_t)k * 128 + ch);
    #pragma unroll
    for (int u = 0; u < 16; ++u){
      float4 f = wr[u];
      int c = ch + u * 4;
      Bs[c + 0][k] = f2bf(f.x);
      Bs[c + 1][k] = f2bf(f.y);
      Bs[c + 2][k] = f2bf(f.z);
      Bs[c + 3][k] = f2bf(f.w);
    }
  }
  f32x4 acc[4][4];
  #pragma unroll
  for (int i = 0; i < 4; ++i)
    #pragma unroll
    for (int j = 0; j < 4; ++j) acc[i][j] = (f32x4){0.f, 0.f, 0.f, 0.f};

  int lrow = l & 15, lk8 = (l >> 4) * 8;
  for (int kc = 0; kc < 4; ++kc){
    __syncthreads();
    {
      int row = t >> 1, kh = t & 1;
      int gn = node0 + row;
      const float4* src = (const float4*)(x + (size_t)gn * 128 + kc * 32 + kh * 16);
      float4 z = make_float4(0.f, 0.f, 0.f, 0.f);
      float4 f0 = (gn < n) ? src[0] : z;
      float4 f1 = (gn < n) ? src[1] : z;
      float4 f2 = (gn < n) ? src[2] : z;
      float4 f3 = (gn < n) ? src[3] : z;
      uint4 p0, p1;
      p0.x = pack2(f0.x, f0.y); p0.y = pack2(f0.z, f0.w);
      p0.z = pack2(f1.x, f1.y); p0.w = pack2(f1.z, f1.w);
      p1.x = pack2(f2.x, f2.y); p1.y = pack2(f2.z, f2.w);
      p1.z = pack2(f3.x, f3.y); p1.w = pack2(f3.z, f3.w);
      *(uint4*)&As[row][kh * 16]     = p0;
      *(uint4*)&As[row][kh * 16 + 8] = p1;
    }
    __syncthreads();
    bf16x8 a[4], b[4];
    #pragma unroll
    for (int mi = 0; mi < 4; ++mi)
      a[mi] = *(const bf16x8*)&As[wm * 64 + mi * 16 + lrow][lk8];
    #pragma unroll
    for (int ni = 0; ni < 4; ++ni)
      b[ni] = *(const bf16x8*)&Bs[wn * 64 + ni * 16 + lrow][kc * 32 + lk8];
    #pragma unroll
    for (int mi = 0; mi < 4; ++mi)
      #pragma unroll
      for (int ni = 0; ni < 4; ++ni)
        acc[mi][ni] = __builtin_amdgcn_mfma_f32_16x16x32_bf16(a[mi], b[ni], acc[mi][ni], 0, 0, 0);
  }
  __syncthreads();                      // As/Bs dead; T takes over
  int rg = (l >> 4) * 4;
  #pragma unroll
  for (int mi = 0; mi < 4; ++mi)
    #pragma unroll
    for (int j = 0; j < 4; ++j){
      int nl = wm * 64 + mi * 16 + rg + j;
      #pragma unroll
      for (int ni = 0; ni < 4; ++ni)
        T[nl][wn * 64 + ni * 16 + lrow] = f2bf(acc[mi][ni][j]);
    }
  __syncthreads();
  // fused att1 + fp8 row emit: 2 threads/row, 64 ch each (4 heads)
  {
    int r = t >> 1, half = t & 1;
    int gn = node0 + r;
    float ssv[4], ddv[4];
    #pragma unroll
    for (int c = 0; c < 4; ++c){
      int h = half * 4 + c;
      uint4 q0 = *(const uint4*)&T[r][half * 64 + c * 16];
      uint4 q1 = *(const uint4*)&T[r][half * 64 + c * 16 + 8];
      unsigned wv[8] = {q0.x, q0.y, q0.z, q0.w, q1.x, q1.y, q1.z, q1.w};
      float f[16];
      #pragma unroll
      for (int u = 0; u < 8; ++u){ f[2 * u] = lof(wv[u]); f[2 * u + 1] = hif(wv[u]); }
      float ss = 0.f, dd = 0.f;
      #pragma unroll
      for (int u = 0; u < 16; ++u){
        ss = fmaf(f[u], asw[h * 16 + u], ss);
        dd = fmaf(f[u], adw[h * 16 + u], dd);
      }
      ssv[c] = ss; ddv[c] = dd;
      uint4 pk;
      pk.x = (unsigned)__builtin_amdgcn_cvt_pk_fp8_f32(f[0],  f[1],  0, 0);
      pk.x = (unsigned)__builtin_amdgcn_cvt_pk_fp8_f32(f[2],  f[3],  (int)pk.x, 1);
      pk.y = (unsigned)__builtin_amdgcn_cvt_pk_fp8_f32(f[4],  f[5],  0, 0);
      pk.y = (unsigned)__builtin_amdgcn_cvt_pk_fp8_f32(f[6],  f[7],  (int)pk.y, 1);
      pk.z = (unsigned)__builtin_amdgcn_cvt_pk_fp8_f32(f[8],  f[9],  0, 0);
      pk.z = (unsigned)__builtin_amdgcn_cvt_pk_fp8_f32(f[10], f[11], (int)pk.z, 1);
      pk.w = (unsigned)__builtin_amdgcn_cvt_pk_fp8_f32(f[12], f[13], 0, 0);
      pk.w = (unsigned)__builtin_amdgcn_cvt_pk_fp8_f32(f[14], f[15], (int)pk.w, 1);
      if (gn < n) *(uint4*)(hq + (size_t)gn * 128 + half * 64 + c * 16) = pk;
    }
    if (gn < n){
      *(float4*)(a_s1 + (size_t)gn * 8 + half * 4) = make_float4(ssv[0], ssv[1], ssv[2], ssv[3]);
      *(float4*)(a_d1 + (size_t)gn * 8 + half * 4) = make_float4(ddv[0], ddv[1], ddv[2], ddv[3]);
    }
  }
}

// ---------------- agg1: fp8 rows, 4 edge-groups of 16 lanes (uint2 = 8 ch/lane) ----------------
__global__ __launch_bounds__(256) void k_agg1(const unsigned char* __restrict__ hq, const float* __restrict__ a_s,
    const float* __restrict__ a_d, const int* __restrict__ col,
    const int* __restrict__ excl, const int* __restrict__ deg,
    const float* __restrict__ b1, unsigned short* __restrict__ out1b, int n){
  int tl = threadIdx.x & 63;
  int node = blockIdx.x * 4 + (threadIdx.x >> 6);
  if (node >= n) return;
  int g  = tl >> 4;          // edge group 0..3
  int il = tl & 15;          // channels [8il, 8il+8)
  int h  = il >> 1;
  float adn = a_d[(size_t)node * 8 + h];
  float a0 = 0.f, a1 = 0.f, a2 = 0.f, a3 = 0.f, a4 = 0.f, a5 = 0.f, a6 = 0.f, a7 = 0.f;
  float denom = 0.f;
  if (g == 0){
    float wSelf = lrelu_exp(a_s[(size_t)node * 8 + h] + adn);
    uint2 hv = *(const uint2*)(hq + (size_t)node * 128 + il * 8);
    f32x2 l0 = __builtin_amdgcn_cvt_pk_f32_fp8((int)hv.x, false);
    f32x2 h0 = __builtin_amdgcn_cvt_pk_f32_fp8((int)hv.x, true);
    f32x2 l1 = __builtin_amdgcn_cvt_pk_f32_fp8((int)hv.y, false);
    f32x2 h1 = __builtin_amdgcn_cvt_pk_f32_fp8((int)hv.y, true);
    a0 = wSelf * l0[0]; a1 = wSelf * l0[1]; a2 = wSelf * h0[0]; a3 = wSelf * h0[1];
    a4 = wSelf * l1[0]; a5 = wSelf * l1[1]; a6 = wSelf * h1[0]; a7 = wSelf * h1[1];
    denom = wSelf;
  }
  int pp = excl[node];
  int end = pp + deg[node];
  for (; pp + 16 <= end; pp += 16){
    int s[4]; float as[4]; uint2 v[4];
    #pragma unroll
    for (int u = 0; u < 4; ++u) s[u] = col[pp + 4 * u + g];
    #pragma unroll
    for (int u = 0; u < 4; ++u) as[u] = a_s[(size_t)s[u] * 8 + h];
    #pragma unroll
    for (int u = 0; u < 4; ++u) v[u] = *(const uint2*)(hq + (size_t)s[u] * 128 + il * 8);
    #pragma unroll
    for (int u = 0; u < 4; ++u){
      float w = lrelu_exp(as[u] + adn);
      f32x2 l0 = __builtin_amdgcn_cvt_pk_f32_fp8((int)v[u].x, false);
      f32x2 h0 = __builtin_amdgcn_cvt_pk_f32_fp8((int)v[u].x, true);
      f32x2 l1 = __builtin_amdgcn_cvt_pk_f32_fp8((int)v[u].y, false);
      f32x2 h1 = __builtin_amdgcn_cvt_pk_f32_fp8((int)v[u].y, true);
      a0 = fmaf(w, l0[0], a0); a1 = fmaf(w, l0[1], a1);
      a2 = fmaf(w, h0[0], a2); a3 = fmaf(w, h0[1], a3);
      a4 = fmaf(w, l1[0], a4); a5 = fmaf(w, l1[1], a5);
      a6 = fmaf(w, h1[0], a6); a7 = fmaf(w, h1[1], a7);
      denom += w;
    }
  }
  for (; pp + 4 <= end; pp += 4){
    int s0 = col[pp + g];
    float w = lrelu_exp(a_s[(size_t)s0 * 8 + h] + adn);
    uint2 v0 = *(const uint2*)(hq + (size_t)s0 * 128 + il * 8);
    f32x2 l0 = __builtin_amdgcn_cvt_pk_f32_fp8((int)v0.x, false);
    f32x2 h0 = __builtin_amdgcn_cvt_pk_f32_fp8((int)v0.x, true);
    f32x2 l1 = __builtin_amdgcn_cvt_pk_f32_fp8((int)v0.y, false);
    f32x2 h1 = __builtin_amdgcn_cvt_pk_f32_fp8((int)v0.y, true);
    a0 = fmaf(w, l0[0], a0); a1 = fmaf(w, l0[1], a1);
    a2 = fmaf(w, h0[0], a2); a3 = fmaf(w, h0[1], a3);
    a4 = fmaf(w, l1[0], a4); a5 = fmaf(w, l1[1], a5);
    a6 = fmaf(w, h1[0], a6); a7 = fmaf(w, h1[1], a7);
    denom += w;
  }
  if (pp + g < end){
    int s0 = col[pp + g];
    float w = lrelu_exp(a_s[(size_t)s0 * 8 + h] + adn);
    uint2 v0 = *(const uint2*)(hq + (size_t)s0 * 128 + il * 8);
    f32x2 l0 = __builtin_amdgcn_cvt_pk_f32_fp8((int)v0.x, false);
    f32x2 h0 = __builtin_amdgcn_cvt_pk_f32_fp8((int)v0.x, true);
    f32x2 l1 = __builtin_amdgcn_cvt_pk_f32_fp8((int)v0.y, false);
    f32x2 h1 = __builtin_amdgcn_cvt_pk_f32_fp8((int)v0.y, true);
    a0 = fmaf(w, l0[0], a0); a1 = fmaf(w, l0[1], a1);
    a2 = fmaf(w, h0[0], a2); a3 = fmaf(w, h0[1], a3);
    a4 = fmaf(w, l1[0], a4); a5 = fmaf(w, l1[1], a5);
    a6 = fmaf(w, h1[0], a6); a7 = fmaf(w, h1[1], a7);
    denom += w;
  }
  #pragma unroll
  for (int off = 16; off <= 32; off <<= 1){
    a0 += __shfl_xor(a0, off); a1 += __shfl_xor(a1, off);
    a2 += __shfl_xor(a2, off); a3 += __shfl_xor(a3, off);
    a4 += __shfl_xor(a4, off); a5 += __shfl_xor(a5, off);
    a6 += __shfl_xor(a6, off); a7 += __shfl_xor(a7, off);
    denom += __shfl_xor(denom, off);
  }
  float inv = 1.0f / denom;
  float4 bb0 = *(const float4*)(b1 + il * 8);
  float4 bb1 = *(const float4*)(b1 + il * 8 + 4);
  float o0 = fmaf(a0, inv, bb0.x); o0 = o0 > 0.f ? o0 : 0.f;
  float o1 = fmaf(a1, inv, bb0.y); o1 = o1 > 0.f ? o1 : 0.f;
  float o2 = fmaf(a2, inv, bb0.z); o2 = o2 > 0.f ? o2 : 0.f;
  float o3 = fmaf(a3, inv, bb0.w); o3 = o3 > 0.f ? o3 : 0.f;
  float o4 = fmaf(a4, inv, bb1.x); o4 = o4 > 0.f ? o4 : 0.f;
  float o5 = fmaf(a5, inv, bb1.y); o5 = o5 > 0.f ? o5 : 0.f;
  float o6 = fmaf(a6, inv, bb1.z); o6 = o6 > 0.f ? o6 : 0.f;
  float o7 = fmaf(a7, inv, bb1.w); o7 = o7 > 0.f ? o7 : 0.f;
  if (g == 0){
    uint4 o;
    o.x = pack2(o0, o1); o.y = pack2(o2, o3);
    o.z = pack2(o4, o5); o.w = pack2(o6, o7);
    *(uint4*)(out1b + (size_t)node * 128 + il * 8) = o;
  }
}

// ---------------- gemm2 + fused att2 -> fp8 rows [N][64B] with a_s embedded at byte 40 ----------------
__global__ __launch_bounds__(256) void k_gemm2a(const unsigned short* __restrict__ ab, const float* __restrict__ W2,
                                                const float* __restrict__ asw2, const float* __restrict__ adw2,
                                                unsigned char* __restrict__ h2q,
                                                float* __restrict__ a_d, int n){
  __shared__ unsigned short xs[32][256];   // 16 KB (bf16); epilogue alias: RB[256][64] bytes
  __shared__ float ws[128][40];            // 20 KB
  __shared__ float ssb[256], ddb[256];     // 2 KB
  int t = threadIdx.x;
  for (int i = t; i < 128 * 40; i += 256) (&ws[0][0])[i] = W2[i];
  ssb[t] = 0.f; ddb[t] = 0.f;
  int ng = t & 63, cg = t >> 6;
  int node0 = blockIdx.x * 256;
  float acc[4][10];
  #pragma unroll
  for (int i = 0; i < 4; ++i)
    #pragma unroll
    for (int j = 0; j < 10; ++j) acc[i][j] = 0.0f;

  for (int kc = 0; kc < 4; ++kc){
    int k0 = kc * 32;
    __syncthreads();
    {
      int gn = node0 + t;
      uint4 q0, q1, r0, r1;
      uint4 z = make_uint4(0, 0, 0, 0);
      if (gn < n){
        const uint4* src = (const uint4*)(ab + (size_t)gn * 128 + k0);
        q0 = src[0]; q1 = src[1]; r0 = src[2]; r1 = src[3];
      } else { q0 = z; q1 = z; r0 = z; r1 = z; }
      unsigned w16[8] = {q0.x, q0.y, q0.z, q0.w, q1.x, q1.y, q1.z, q1.w};
      #pragma unroll
      for (int j = 0; j < 8; ++j){
        xs[j * 2][t]     = (unsigned short)(w16[j] & 0xffffu);
        xs[j * 2 + 1][t] = (unsigned short)(w16[j] >> 16);
      }
      unsigned w16b[8] = {r0.x, r0.y, r0.z, r0.w, r1.x, r1.y, r1.z, r1.w};
      #pragma unroll
      for (int j = 0; j < 8; ++j){
        xs[16 + j * 2][t]     = (unsigned short)(w16b[j] & 0xffffu);
        xs[16 + j * 2 + 1][t] = (unsigned short)(w16b[j] >> 16);
      }
    }
    __syncthreads();
    #pragma unroll 4
    for (int k = 0; k < 32; ++k){
      float xv[4];
      #pragma unroll
      for (int i = 0; i < 4; ++i) xv[i] = __uint_as_float(((unsigned)xs[k][ng + 64 * i]) << 16);
      float wv[10];
      #pragma unroll
      for (int j = 0; j < 10; ++j) wv[j] = ws[k0 + k][cg * 10 + j];
      #pragma unroll
      for (int i = 0; i < 4; ++i)
        #pragma unroll
        for (int j = 0; j < 10; ++j) acc[i][j] = fmaf(xv[i], wv[j], acc[i][j]);
    }
  }
  // fused att2 partial dots
  float asl[10], adl[10];
  #pragma unroll
  for (int j = 0; j < 10; ++j){ asl[j] = asw2[cg * 10 + j]; adl[j] = adw2[cg * 10 + j]; }
  #pragma unroll
  for (int i = 0; i < 4; ++i){
    float ssi = 0.f, ddi = 0.f;
    #pragma unroll
    for (int j = 0; j < 10; ++j){
      ssi = fmaf(acc[i][j], asl[j], ssi);
      ddi = fmaf(acc[i][j], adl[j], ddi);
    }
    atomicAdd(&ssb[ng + 64 * i], ssi);
    atomicAdd(&ddb[ng + 64 * i], ddi);
  }
  __syncthreads();                         // xs dead, ssb/ddb final
  unsigned char* RB = (unsigned char*)xs;  // 256 rows x 64 B
  #pragma unroll
  for (int i = 0; i < 4; ++i){
    int row = ng + 64 * i;
    unsigned char* dst = &RB[row * 64 + cg * 10];
    #pragma unroll
    for (int j = 0; j < 10; j += 2){
      int p2 = __builtin_amdgcn_cvt_pk_fp8_f32(acc[i][j], acc[i][j + 1], 0, 0);
      dst[j]     = (unsigned char)(p2 & 0xff);
      dst[j + 1] = (unsigned char)((p2 >> 8) & 0xff);
    }
  }
  *(float*)&RB[t * 64 + 40] = ssb[t];      // embed a_s at byte 40
  __syncthreads();
  {
    int gn = node0 + t;
    if (gn < n){
      a_d[gn] = ddb[t];
      uint4* drow = (uint4*)(h2q + (size_t)gn * 64);
      const uint4* srow = (const uint4*)&RB[t * 64];
      drow[0] = srow[0]; drow[1] = srow[1]; drow[2] = srow[2]; drow[3] = srow[3];
    }
  }
}

// ---------------- agg2 + log_softmax: 64B fp8 rows, 4 edge-groups of 16 lanes ----------------
__global__ __launch_bounds__(256) void k_agg2(const unsigned char* __restrict__ h2q,
    const float* __restrict__ a_d, const int* __restrict__ col,
    const int* __restrict__ excl, const int* __restrict__ deg,
    const float* __restrict__ b2, float* __restrict__ out, int n){
  int tl = threadIdx.x & 63;
  int node = blockIdx.x * 4 + (threadIdx.x >> 6);
  if (node >= n) return;
  int g = tl >> 4, il = tl & 15;
  bool ld  = il < 11;
  bool act = il < 10;                      // channels 4il..4il+3 (< 40)
  float adn = a_d[node];
  float a0 = 0.f, a1 = 0.f, a2 = 0.f, a3 = 0.f, denom = 0.f;
  if (g == 0){
    const unsigned* sr = (const unsigned*)(h2q + (size_t)node * 64);
    unsigned hv = ld ? sr[il] : 0u;
    float asf = __uint_as_float(__shfl(hv, 10));
    float wSelf = lrelu_exp(asf + adn);
    f32x2 lo = __builtin_amdgcn_cvt_pk_f32_fp8((int)hv, false);
    f32x2 hi = __builtin_amdgcn_cvt_pk_f32_fp8((int)hv, true);
    a0 = wSelf * lo[0]; a1 = wSelf * lo[1];
    a2 = wSelf * hi[0]; a3 = wSelf * hi[1];
    denom = wSelf;
  }
  int pp = excl[node];
  int end = pp + deg[node];
  for (; pp + 16 <= end; pp += 16){
    int s[4]; unsigned v[4];
    #pragma unroll
    for (int u = 0; u < 4; ++u) s[u] = col[pp + 4 * u + g];
    #pragma unroll
    for (int u = 0; u < 4; ++u) v[u] = ld ? *(const unsigned*)(h2q + (size_t)s[u] * 64 + il * 4) : 0u;
    #pragma unroll
    for (int u = 0; u < 4; ++u){
      float asf = __uint_as_float(__shfl(v[u], (g << 4) + 10));
      float w = lrelu_exp(asf + adn);
      f32x2 lo = __builtin_amdgcn_cvt_pk_f32_fp8((int)v[u], false);
      f32x2 hi = __builtin_amdgcn_cvt_pk_f32_fp8((int)v[u], true);
      a0 = fmaf(w, lo[0], a0); a1 = fmaf(w, lo[1], a1);
      a2 = fmaf(w, hi[0], a2); a3 = fmaf(w, hi[1], a3);
      denom += w;
    }
  }
  for (; pp + 4 <= end; pp += 4){
    int s0 = col[pp + g];
    unsigned v0 = ld ? *(const unsigned*)(h2q + (size_t)s0 * 64 + il * 4) : 0u;
    float asf = __uint_as_float(__shfl(v0, (g << 4) + 10));
    float w = lrelu_exp(asf + adn);
    f32x2 lo = __builtin_amdgcn_cvt_pk_f32_fp8((int)v0, false);
    f32x2 hi = __builtin_amdgcn_cvt_pk_f32_fp8((int)v0, true);
    a0 = fmaf(w, lo[0], a0); a1 = fmaf(w, lo[1], a1);
    a2 = fmaf(w, hi[0], a2); a3 = fmaf(w, hi[1], a3);
    denom += w;
  }
  if (pp + g < end){
    int s0 = col[pp + g];
    unsigned v0 = ld ? *(const unsigned*)(h2q + (size_t)s0 * 64 + il * 4) : 0u;
    float asf = __uint_as_float(__shfl(v0, (g << 4) + 10));
    float w = lrelu_exp(asf + adn);
    f32x2 lo = __builtin_amdgcn_cvt_pk_f32_fp8((int)v0, false);
    f32x2 hi = __builtin_amdgcn_cvt_pk_f32_fp8((int)v0, true);
    a0 = fmaf(w, lo[0], a0); a1 = fmaf(w, lo[1], a1);
    a2 = fmaf(w, hi[0], a2); a3 = fmaf(w, hi[1], a3);
    denom += w;
  }
  #pragma unroll
  for (int off = 16; off <= 32; off <<= 1){
    a0 += __shfl_xor(a0, off); a1 += __shfl_xor(a1, off);
    a2 += __shfl_xor(a2, off); a3 += __shfl_xor(a3, off);
    denom += __shfl_xor(denom, off);
  }
  float inv = 1.0f / denom;
  float4 bb = act ? *(const float4*)(b2 + il * 4) : make_float4(0.f, 0.f, 0.f, 0.f);
  float v0 = act ? fmaf(a0, inv, bb.x) : -1e30f;
  float v1 = act ? fmaf(a1, inv, bb.y) : -1e30f;
  float v2 = act ? fmaf(a2, inv, bb.z) : -1e30f;
  float v3 = act ? fmaf(a3, inv, bb.w) : -1e30f;
  float m = fmaxf(fmaxf(v0, v1), fmaxf(v2, v3));
  #pragma unroll
  for (int off = 8; off >= 1; off >>= 1) m = fmaxf(m, __shfl_xor(m, off));
  float S = act ? (__expf(v0 - m) + __expf(v1 - m) + __expf(v2 - m) + __expf(v3 - m)) : 0.f;
  #pragma unroll
  for (int off = 8; off >= 1; off >>= 1) S += __shfl_xor(S, off);
  float ls = __logf(S);
  if (act && g == 0){
    *(float4*)(out + (size_t)node * 40 + il * 4) =
      make_float4(v0 - m - ls, v1 - m - ls, v2 - m - ls, v3 - m - ls);
  }
}

extern "C" void kernel_launch(void* const* d_in, const int* in_sizes, int n_in,
                              void* d_out, int out_size, void* d_ws, size_t ws_size,
                              hipStream_t stream){
  const float* x    = (const float*)d_in[0];
  const int*   ei   = (const int*)d_in[1];          // int32 (jax x64 disabled)
  const float* W1   = (const float*)d_in[2];
  const float* as1w = (const float*)d_in[3];
  const float* ad1w = (const float*)d_in[4];
  const float* b1   = (const float*)d_in[5];
  const float* W2   = (const float*)d_in[6];
  const float* as2w = (const float*)d_in[7];
  const float* ad2w = (const float*)d_in[8];
  const float* b2   = (const float*)d_in[9];
  float* out = (float*)d_out;
  const int N = in_sizes[0] / 128;
  const int E = in_sizes[1] / 2;

  const int NBK = (N + 255) / 256;        // node buckets of 256
  const int B   = (E + 8191) / 8192;      // edge chunks of 8192
  const int total = NBK * B;
  const int nsc = (total + 2047) / 2048;  // scan blocks

  char* p = (char*)d_ws;
  auto alloc = [&](size_t bytes) -> void* {
    void* r = (void*)p;
    p += (bytes + 511) & ~(size_t)511;
    return r;
  };
  int*            deg      = (int*)           alloc((size_t)N * 4);
  int*            excl     = (int*)           alloc((size_t)N * 4);
  int*            counts   = (int*)           alloc((size_t)total * 4);
  int*            bstart   = (int*)           alloc((size_t)(NBK + 1) * 4);
  int*            partials = (int*)           alloc(64 * 4);
  int2*           pairs    = (int2*)          alloc((size_t)E * 8);
  int*            col      = (int*)           alloc((size_t)E * 4);
  float*          a_s1     = (float*)         alloc((size_t)N * 8 * 4);
  float*          a_d1     = (float*)         alloc((size_t)N * 8 * 4);
  unsigned short* out1b    = (unsigned short*)alloc((size_t)N * 128 * 2);
  unsigned char*  h1q      = (unsigned char*) alloc((size_t)N * 128);
  // layer-2 temporaries overlay h1q (dead after agg1): h2q = N*64 bytes
  unsigned char*  h2q  = h1q;
  float*          a_d2 = (float*)(h1q + (size_t)N * 64 + 256);

  int nG1 = (N + 127) / 128;

  k_gemm1 <<<nG1, 256, 0, stream>>>(x, W1, as1w, ad1w, h1q, a_s1, a_d1, N);
  k_cnt   <<<B, 256, 0, stream>>>(ei, E, N, counts, B, NBK);
  k_s1    <<<nsc, 256, 0, stream>>>(counts, total, partials);
  k_s2    <<<1, 64, 0, stream>>>(partials, nsc, bstart, NBK);
  k_s3    <<<(total + 255) / 256, 256, 0, stream>>>(counts, total, partials, B, bstart);
  k_bscat <<<B, 256, 0, stream>>>(ei, E, N, counts, B, pairs, NBK);
  k_bucket<<<NBK, 256, 0, stream>>>(pairs, bstart, N, deg, excl, col);
  k_agg1  <<<(N + 3) / 4, 256, 0, stream>>>(h1q, a_s1, a_d1, col, excl, deg, b1, out1b, N);
  k_gemm2a<<<(N + 255) / 256, 256, 0, stream>>>(out1b, W2, as2w, ad2w, h2q, a_d2, N);
  k_agg2  <<<(N + 3) / 4, 256, 0, stream>>>(h2q, a_d2, col, excl, deg, b2, out, N);
}